// Round 7
// baseline (108.126 us; speedup 1.0000x reference)
//
#include <hip/hip_runtime.h>
#include <hip/hip_bf16.h>

// Problem geometry (fixed by the reference)
constexpr int B = 16, K = 100, H = 120, W = 160;
constexpr int HW  = H * W;          // 19200
constexpr int NF4 = HW / 4;         // 4800 float4 per map
constexpr int BK  = B * K;          // 1600 maps per tensor
constexpr int W4  = W / 4;          // 40 float4 per row

// Flat f32 output layout (concatenated in reference return order)
constexpr size_t OFF_DK   = 0;                       // Dk        [B,K,H,W]
constexpr size_t OFF_KP   = (size_t)BK * HW;         // keypoint  [B,3K,3]
constexpr size_t OFF_ZETA = OFF_KP + (size_t)B*3*K*3;// get_zeta  [B,K]
constexpr size_t OFF_TFDK = OFF_ZETA + BK;           // tf_Dk     [B,K,H,W]
constexpr size_t OFF_TFKP = OFF_TFDK + (size_t)BK*HW;// tf_keypoint [B,3K,3]

constexpr int TPB = 128;   // 128-thr blocks: 3200 blocks = 25 waves/CU, ALL
                           // resident at t=0 (no 8-blocks/CU generation tail
                           // that 256-thr blocks had at 12.5 blocks/CU)

typedef float f32x4 __attribute__((ext_vector_type(4)));
typedef float f32x2 __attribute__((ext_vector_type(2)));

// native-rate sigmoid: rcp(1 + exp2(-x*log2e)); identical sequence everywhere
// so recomputed gathers are bit-identical to the stored map values.
__device__ __forceinline__ float fast_sigmoid(float x) {
    const float e = __builtin_amdgcn_exp2f(-1.44269504088896340736f * x);
    return __builtin_amdgcn_rcpf(1.0f + e);
}

// Single fused kernel: sigmoid stream + per-map reduction + keypoint row.
// grid.x = 2*BK blocks; block handles one (tensor, b, k) map.
__global__ __launch_bounds__(TPB)
void fused_kernel(const float* __restrict__ Rk,
                  const float* __restrict__ tfRk,
                  float* __restrict__ out) {
    const int blk    = blockIdx.x;
    const int tensor = (blk >= BK) ? 1 : 0;
    const int bk     = blk - tensor * BK;
    const float* src = tensor ? tfRk : Rk;
    float*       dst = out + (tensor ? OFF_TFDK : OFF_DK);

    const f32x4* __restrict__ s4 = (const f32x4*)(src + (size_t)bk * HW);
    f32x4*       __restrict__ d4 = (f32x4*)(dst + (size_t)bk * HW);

    const int tid = threadIdx.x;
    f32x2 sum2 = {0.0f, 0.0f}, sx2 = {0.0f, 0.0f}, sy2 = {0.0f, 0.0f};

    for (int i = tid; i < NF4; i += TPB) {
        f32x4 v = s4[i];
        f32x4 o;
        o.x = fast_sigmoid(v.x);
        o.y = fast_sigmoid(v.y);
        o.z = fast_sigmoid(v.z);
        o.w = fast_sigmoid(v.w);
        d4[i] = o;

        const int y  = i / W4;
        const int x0 = (i - y * W4) * 4;
        const float fy = (float)y, fx0 = (float)x0;

        const f32x2 lo = {o.x, o.y}, hi = {o.z, o.w};
        const f32x2 rs = lo + hi;
        sum2 += rs;
        const f32x2 yy = {fy, fy};
        sy2 = rs * yy + sy2;                            // v_pk_fma_f32
        const f32x2 xlo = {fx0,        fx0 + 1.0f};
        const f32x2 xhi = {fx0 + 2.0f, fx0 + 3.0f};
        sx2 = lo * xlo + sx2;
        sx2 = hi * xhi + sx2;
    }

    float sum = sum2.x + sum2.y;
    float sx  = sx2.x + sx2.y;
    float sy  = sy2.x + sy2.y;

    // wave (64-lane) reduction
    for (int off = 32; off > 0; off >>= 1) {
        sum += __shfl_down(sum, off);
        sx  += __shfl_down(sx,  off);
        sy  += __shfl_down(sy,  off);
    }
    __shared__ float red[3][TPB / 64];
    const int wave = tid >> 6, lane = tid & 63;
    if (lane == 0) { red[0][wave] = sum; red[1][wave] = sx; red[2][wave] = sy; }
    __syncthreads();

    if (tid == 0) {
        const float S = red[0][0] + red[0][1];
        const float X = red[1][0] + red[1][1];
        const float Y = red[2][0] + red[2][1];

        const int b = bk / K, k = bk - b * K;
        if (tensor == 0) out[OFF_ZETA + bk] = S;

        const float kx = rintf(X / S);   // RNE matches jnp.round
        const float ky = rintf(Y / S);

        // gathers from the INPUTS, sigmoid recomputed (bit-identical)
        const float* imap  = src + (size_t)bk * HW;   // own map (s, s1)
        const float* imain = Rk  + (size_t)bk * HW;   // main map (s2, bug-faithful)

        const int gx = (int)kx, gy = (int)ky;
        const float s = fast_sigmoid(imap[gy * W + gx]);

        // mul then add (NOT fma) to match jnp's kp + kp*s, then int32 truncation
        const int kp1x = (int)__fadd_rn(kx, __fmul_rn(kx, s));
        const int kp1y = (int)__fadd_rn(ky, __fmul_rn(ky, s));
        const int kp2x = (int)__fsub_rn(kx, __fmul_rn(kx, s));
        const int kp2y = (int)__fsub_rn(ky, __fmul_rn(ky, s));

        const int w1 = min(max(kp1x, 0), W - 1), h1 = min(max(kp1y, 0), H - 1);
        const int w2 = min(max(kp2x, 0), W - 1), h2 = min(max(kp2y, 0), H - 1);
        const float s1 = fast_sigmoid(imap [h1 * W + w1]);
        const float s2 = fast_sigmoid(imain[h2 * W + w2]);

        float* okp = out + (tensor ? OFF_TFKP : OFF_KP);
        float* r0 = okp + ((size_t)b * 3 * K + k) * 3;
        r0[0] = kx;           r0[1] = ky;           r0[2] = s;
        float* r1 = okp + ((size_t)b * 3 * K + K + k) * 3;
        r1[0] = (float)kp1x;  r1[1] = (float)kp1y;  r1[2] = s1;
        float* r2 = okp + ((size_t)b * 3 * K + 2 * K + k) * 3;
        r2[0] = (float)kp2x;  r2[1] = (float)kp2y;  r2[2] = s2;
    }
}

extern "C" void kernel_launch(void* const* d_in, const int* in_sizes, int n_in,
                              void* d_out, int out_size, void* d_ws, size_t ws_size,
                              hipStream_t stream) {
    const float* Rk   = (const float*)d_in[0];
    const float* tfRk = (const float*)d_in[1];
    float* out = (float*)d_out;

    fused_kernel<<<2 * BK, TPB, 0, stream>>>(Rk, tfRk, out);
}

// Round 8
// 106.868 us; speedup vs baseline: 1.0118x; 1.0118x over previous
//
#include <hip/hip_runtime.h>
#include <hip/hip_bf16.h>

// Problem geometry (fixed by the reference)
constexpr int B = 16, K = 100, H = 120, W = 160;
constexpr int HW  = H * W;          // 19200
constexpr int NF4 = HW / 4;         // 4800 float4 per map
constexpr int BK  = B * K;          // 1600 maps per tensor
constexpr int W4  = W / 4;          // 40 float4 per row

// Flat f32 output layout (concatenated in reference return order)
constexpr size_t OFF_DK   = 0;                       // Dk        [B,K,H,W]
constexpr size_t OFF_KP   = (size_t)BK * HW;         // keypoint  [B,3K,3]
constexpr size_t OFF_ZETA = OFF_KP + (size_t)B*3*K*3;// get_zeta  [B,K]
constexpr size_t OFF_TFDK = OFF_ZETA + BK;           // tf_Dk     [B,K,H,W]
constexpr size_t OFF_TFKP = OFF_TFDK + (size_t)BK*HW;// tf_keypoint [B,3K,3]

constexpr int TPB = 256;   // measured best (r6: 105.7 vs r7 TPB=128: 108.1)

typedef float f32x4 __attribute__((ext_vector_type(4)));
typedef float f32x2 __attribute__((ext_vector_type(2)));

// native-rate sigmoid: rcp(1 + exp2(-x*log2e)); identical sequence everywhere
// so recomputed gathers are bit-identical to the stored map values.
__device__ __forceinline__ float fast_sigmoid(float x) {
    const float e = __builtin_amdgcn_exp2f(-1.44269504088896340736f * x);
    return __builtin_amdgcn_rcpf(1.0f + e);
}

// Single fused kernel: sigmoid stream + per-map reduction + keypoint row.
// grid.x = 2*BK blocks; block handles one (tensor, b, k) map.
// 1-deep rotate prefetch: next iteration's load is issued BEFORE current
// compute+store, keeping one load in flight through the compute phase.
__global__ __launch_bounds__(TPB)
void fused_kernel(const float* __restrict__ Rk,
                  const float* __restrict__ tfRk,
                  float* __restrict__ out) {
    const int blk    = blockIdx.x;
    const int tensor = (blk >= BK) ? 1 : 0;
    const int bk     = blk - tensor * BK;
    const float* src = tensor ? tfRk : Rk;
    float*       dst = out + (tensor ? OFF_TFDK : OFF_DK);

    const f32x4* __restrict__ s4 = (const f32x4*)(src + (size_t)bk * HW);
    f32x4*       __restrict__ d4 = (f32x4*)(dst + (size_t)bk * HW);

    const int tid = threadIdx.x;
    f32x2 sum2 = {0.0f, 0.0f}, sx2 = {0.0f, 0.0f}, sy2 = {0.0f, 0.0f};

    f32x4 v = {};
    if (tid < NF4) v = s4[tid];                    // prologue load (always true)

    for (int i = tid; i < NF4; i += TPB) {
        const int inext = i + TPB;
        f32x4 vn = {};
        if (inext < NF4) vn = s4[inext];           // prefetch next BEFORE compute

        f32x4 o;
        o.x = fast_sigmoid(v.x);
        o.y = fast_sigmoid(v.y);
        o.z = fast_sigmoid(v.z);
        o.w = fast_sigmoid(v.w);
        d4[i] = o;

        const int y  = i / W4;
        const int x0 = (i - y * W4) * 4;
        const float fy = (float)y, fx0 = (float)x0;

        const f32x2 lo = {o.x, o.y}, hi = {o.z, o.w};
        const f32x2 rs = lo + hi;
        sum2 += rs;
        const f32x2 yy = {fy, fy};
        sy2 = rs * yy + sy2;                       // v_pk_fma_f32
        const f32x2 xlo = {fx0,        fx0 + 1.0f};
        const f32x2 xhi = {fx0 + 2.0f, fx0 + 3.0f};
        sx2 = lo * xlo + sx2;
        sx2 = hi * xhi + sx2;

        v = vn;
    }

    float sum = sum2.x + sum2.y;
    float sx  = sx2.x + sx2.y;
    float sy  = sy2.x + sy2.y;

    // wave (64-lane) reduction
    for (int off = 32; off > 0; off >>= 1) {
        sum += __shfl_down(sum, off);
        sx  += __shfl_down(sx,  off);
        sy  += __shfl_down(sy,  off);
    }
    __shared__ float red[3][TPB / 64];
    const int wave = tid >> 6, lane = tid & 63;
    if (lane == 0) { red[0][wave] = sum; red[1][wave] = sx; red[2][wave] = sy; }
    __syncthreads();

    if (tid == 0) {
        float S = 0.0f, X = 0.0f, Y = 0.0f;
        #pragma unroll
        for (int wv = 0; wv < TPB / 64; ++wv) {
            S += red[0][wv]; X += red[1][wv]; Y += red[2][wv];
        }

        const int b = bk / K, k = bk - b * K;
        if (tensor == 0) out[OFF_ZETA + bk] = S;

        const float kx = rintf(X / S);   // RNE matches jnp.round
        const float ky = rintf(Y / S);

        // gathers from the INPUTS, sigmoid recomputed (bit-identical)
        const float* imap  = src + (size_t)bk * HW;   // own map (s, s1)
        const float* imain = Rk  + (size_t)bk * HW;   // main map (s2, bug-faithful)

        const int gx = (int)kx, gy = (int)ky;
        const float s = fast_sigmoid(imap[gy * W + gx]);

        // mul then add (NOT fma) to match jnp's kp + kp*s, then int32 truncation
        const int kp1x = (int)__fadd_rn(kx, __fmul_rn(kx, s));
        const int kp1y = (int)__fadd_rn(ky, __fmul_rn(ky, s));
        const int kp2x = (int)__fsub_rn(kx, __fmul_rn(kx, s));
        const int kp2y = (int)__fsub_rn(ky, __fmul_rn(ky, s));

        const int w1 = min(max(kp1x, 0), W - 1), h1 = min(max(kp1y, 0), H - 1);
        const int w2 = min(max(kp2x, 0), W - 1), h2 = min(max(kp2y, 0), H - 1);
        const float s1 = fast_sigmoid(imap [h1 * W + w1]);
        const float s2 = fast_sigmoid(imain[h2 * W + w2]);

        float* okp = out + (tensor ? OFF_TFKP : OFF_KP);
        float* r0 = okp + ((size_t)b * 3 * K + k) * 3;
        r0[0] = kx;           r0[1] = ky;           r0[2] = s;
        float* r1 = okp + ((size_t)b * 3 * K + K + k) * 3;
        r1[0] = (float)kp1x;  r1[1] = (float)kp1y;  r1[2] = s1;
        float* r2 = okp + ((size_t)b * 3 * K + 2 * K + k) * 3;
        r2[0] = (float)kp2x;  r2[1] = (float)kp2y;  r2[2] = s2;
    }
}

extern "C" void kernel_launch(void* const* d_in, const int* in_sizes, int n_in,
                              void* d_out, int out_size, void* d_ws, size_t ws_size,
                              hipStream_t stream) {
    const float* Rk   = (const float*)d_in[0];
    const float* tfRk = (const float*)d_in[1];
    float* out = (float*)d_out;

    fused_kernel<<<2 * BK, TPB, 0, stream>>>(Rk, tfRk, out);
}